// Round 11
// baseline (183.673 us; speedup 1.0000x reference)
//
#include <hip/hip_runtime.h>
#include <hip/hip_cooperative_groups.h>
#include <math.h>

namespace cg = cooperative_groups;

#define NB 32
#define PP 24564
#define MM 32
#define NCLS 81
#define CHUNK 1024
#define MBLK 24          // ceil(PP/CHUNK)
#define PPW 768          // posbit u32 words per image
#define BSH 18           // bin = float_bits >> 18 (4096 bins)
#define HB 4096
#define CAPL 2048        // LDS candidate cap (phase 2)

// ---- workspace layout (bytes); nothing pre-zeroed by host ----
#define WS_DONE   0        // int (zeroed in phase 1 by block (0,0); used in phase 2)
#define WS_PCNT   32       // int[NB]
#define WS_IACC   160      // float4[NB]: {ce,loc,op,hn}
#define WS_PACC   672      // float[NB*MBLK*3] -> ends 9888
#define WS_CPART  9888     // int[NB*MBLK] -> ends 12960
#define WS_BKEYP  12960    // u64[NB*MBLK*MM] -> ends 209568
#define WS_POSBIT 209568   // u32[NB*PPW] -> ends 307872
#define WS_M8     307872   // u8[NB*PP] -> ends 1093920
#define WS_VAL    1093936  // float[NB*PP] 16B-aligned

__device__ __forceinline__ float sl1(float d) {
    float a = fabsf(d);
    return a < 1.0f ? 0.5f * d * d : a - 0.5f;
}
__device__ __forceinline__ unsigned long long u64max(unsigned long long a, unsigned long long b) {
    return a > b ? a : b;
}
__device__ __forceinline__ float locv(const float4& pd, const float4& pb,
                                      float gx1, float gy1, float gx2, float gy2) {
    float pcx = (pb.x + pb.z) * 0.5f, pcy = (pb.y + pb.w) * 0.5f;
    float pw = pb.z - pb.x, ph = pb.w - pb.y;
    float g0 = ((gx1 + gx2) * 0.5f - pcx) / (pw / 10.0f);
    float g1 = ((gy1 + gy2) * 0.5f - pcy) / (ph / 10.0f);
    float g2 = logf((gx2 - gx1) / pw) * 5.0f;
    float g3 = logf((gy2 - gy1) / ph) * 5.0f;
    return sl1(pd.x - g0) + sl1(pd.y - g1) + sl1(pd.z - g2) + sl1(pd.w - g3);
}

// shared memory overlay: phase 1 (match) vs phase 2 (selection)
union SMem {
    struct {
        float4 spri[CHUNK];                 // 16 KB
        unsigned char sm8[CHUNK];
        float bx0[MM], by0[MM], bx1[MM], by1[MM], bar_[MM];
        unsigned long long wk[4][MM];
        int bcnt;
        float sacc[3];
    } p1;
    struct {
        unsigned hist[HB];                  // 16 KB
        unsigned cand[CAPL];                // 8 KB
        unsigned ssc[256];
        unsigned rh[128];
        unsigned fl[MM];
        int newlist[MM];
        float sacc[3];
        float wred[4], wred2[4];
        int nnew, nat, tot;
        int s_c, s_d, s_rem, s_rr;
        unsigned s_cur;
    } p2;
};

extern "C" __global__ void __launch_bounds__(256) k_all(
    const float* __restrict__ priors,
    const float* __restrict__ boxes,
    const float* __restrict__ obj,
    const float* __restrict__ pred_boxes,
    const float* __restrict__ pred_cls,
    const int* __restrict__ labels,
    unsigned long long* __restrict__ bkeyp,
    unsigned int* __restrict__ posbit,
    unsigned char* __restrict__ m8,
    float* __restrict__ val,
    int* __restrict__ cpart,
    float* __restrict__ pacc,
    int* __restrict__ pcnt,
    float4* __restrict__ iacc,
    int* __restrict__ done,
    float* __restrict__ out)
{
    cg::grid_group grid = cg::this_grid();
    const int n = blockIdx.y;
    const int bx = blockIdx.x;
    const int t = threadIdx.x;
    const int lane = t & 63;
    const int wave = t >> 6;
    const int p0 = bx * CHUNK;

    __shared__ SMem sm;

    if (bx == 0 && n == 0 && t == 0) *done = 0;   // used only after grid.sync()

    // ================= PHASE 1: matching + natural-positive losses =================
    {
        float ov[4];
#pragma unroll
        for (int i = 0; i < 4; i++) {
            int p = p0 + t + i * 256;
            float4 v;
            if (p < PP) { v = *(const float4*)(priors + (size_t)p * 4);
                          ov[i] = obj[(size_t)n * PP + p]; }
            else { v.x = 3.f; v.y = 3.f; v.z = 3.5f; v.w = 3.5f; ov[i] = 0.f; }
            sm.p1.spri[t + i * 256] = v;
        }
        if (t < MM) {
            const float* b = boxes + ((size_t)n * MM + t) * 4;
            float x1 = b[0], y1 = b[1], x2 = b[2], y2 = b[3];
            sm.p1.bx0[t] = x1; sm.p1.by0[t] = y1; sm.p1.bx1[t] = x2; sm.p1.by1[t] = y2;
            sm.p1.bar_[t] = (x2 - x1) * (y2 - y1);
        }
        if (t == 0) sm.p1.bcnt = 0;
        if (t < 3) sm.p1.sacc[t] = 0.f;
        __syncthreads();

        float4 pr0 = sm.p1.spri[t], pr1 = sm.p1.spri[t + 256],
               pr2 = sm.p1.spri[t + 512], pr3 = sm.p1.spri[t + 768];
        const float pa0 = (pr0.z - pr0.x) * (pr0.w - pr0.y);
        const float pa1 = (pr1.z - pr1.x) * (pr1.w - pr1.y);
        const float pa2 = (pr2.z - pr2.x) * (pr2.w - pr2.y);
        const float pa3 = (pr3.z - pr3.x) * (pr3.w - pr3.y);
        unsigned pb0 = 0, pb1 = 0, pb2 = 0, pb3 = 0;

#define DO_IOU(PR, PA, PB, ROFF) { \
        float w = fminf(x1, PR.z) - fmaxf(x0, PR.x); \
        float h = fminf(y1, PR.w) - fmaxf(y0, PR.y); \
        w = fmaxf(w, 0.0f); h = fmaxf(h, 0.0f); \
        float inter = w * h; \
        float iou = inter / (ar + PA - inter); \
        unsigned ib = __float_as_uint(iou); \
        unsigned nk = (ib & 0xFFFFFFE0u) | (unsigned)(31 - m); \
        PB = PB > nk ? PB : nk; \
        unsigned long long kk = ((unsigned long long)ib << 32) \
            | (unsigned long long)(0xFFFFFFFFu - (unsigned)(p0 + t + (ROFF))); \
        km = u64max(km, kk); }

#pragma unroll 2
        for (int m = 0; m < MM; m++) {
            const float x0 = sm.p1.bx0[m], y0 = sm.p1.by0[m],
                        x1 = sm.p1.bx1[m], y1 = sm.p1.by1[m], ar = sm.p1.bar_[m];
            unsigned long long km = 0ULL;
            DO_IOU(pr0, pa0, pb0, 0)
            DO_IOU(pr1, pa1, pb1, 256)
            DO_IOU(pr2, pa2, pb2, 512)
            DO_IOU(pr3, pa3, pb3, 768)
#pragma unroll
            for (int d = 1; d < 64; d <<= 1)
                km = u64max(km, (unsigned long long)__shfl_xor(km, d));
            if (lane == 0) sm.p1.wk[wave][m] = km;
        }
#undef DO_IOU

        int cnt = 0;
        unsigned long long bl[4];
#define ROWOUT(PB, R) { \
        int p = p0 + t + (R) * 256; \
        bool pos = (PB >= 0x3F000000u) && (p < PP); \
        unsigned long long ball = __ballot(pos); \
        bl[R] = ball; \
        unsigned char mb = (unsigned char)(31u - (PB & 31u)); \
        sm.p1.sm8[t + (R) * 256] = mb; \
        if (lane == 0) { \
            int wi = n * PPW + ((p0 + (R) * 256 + wave * 64) >> 5); \
            posbit[wi] = (unsigned)ball; posbit[wi + 1] = (unsigned)(ball >> 32); \
            cnt += __popcll(ball); \
        } \
        if (p < PP) { \
            size_t idx = (size_t)n * PP + p; \
            m8[idx] = mb; \
            val[idx] = pos ? 0.f : ov[R] * ov[R]; \
        } }
        ROWOUT(pb0, 0) ROWOUT(pb1, 1) ROWOUT(pb2, 2) ROWOUT(pb3, 3)
#undef ROWOUT
        if (lane == 0 && cnt) atomicAdd(&sm.p1.bcnt, cnt);

        // natural-positive losses inline (half-wave per positive)
        {
            const int half = lane >> 5, hl = lane & 31;
            float ce_s = 0.f, loc_s = 0.f, op_s = 0.f;
#pragma unroll
            for (int R = 0; R < 4; R++) {
                unsigned long long mask = bl[R];
                const int roff = R * 256 + wave * 64;
                while (mask) {
                    int i1 = __ffsll((long long)mask) - 1; mask &= mask - 1;
                    int i2 = -1;
                    if (mask) { i2 = __ffsll((long long)mask) - 1; mask &= mask - 1; }
                    const int pi = half ? i2 : i1;
                    const bool act = pi >= 0;
                    const int poff = roff + (act ? pi : 0);
                    const size_t idx = (size_t)n * PP + p0 + poff;

                    const int bm = sm.p1.sm8[poff];
                    const float* row = pred_cls + idx * NCLS;
                    float a = act ? row[hl] : -INFINITY;
                    float b = act ? row[hl + 32] : -INFINITY;
                    float c = (act && hl < NCLS - 64) ? row[hl + 64] : -INFINITY;
                    float mx = fmaxf(fmaxf(a, b), c);
#pragma unroll
                    for (int d = 1; d < 32; d <<= 1) mx = fmaxf(mx, __shfl_xor(mx, d));
                    float se = act ? (expf(a - mx) + expf(b - mx)
                                      + ((hl < NCLS - 64) ? expf(c - mx) : 0.f)) : 0.f;
#pragma unroll
                    for (int d = 1; d < 32; d <<= 1) se += __shfl_xor(se, d);

                    if (act) {
                        if (hl == 0) {
                            ce_s += mx + logf(se) - row[labels[n * MM + bm]];
                        } else if (hl == 1) {
                            float4 pb = sm.p1.spri[poff];
                            float4 pd = *(const float4*)(pred_boxes + idx * 4);
                            loc_s += locv(pd, pb, sm.p1.bx0[bm], sm.p1.by0[bm],
                                          sm.p1.bx1[bm], sm.p1.by1[bm]);
                        } else if (hl == 2) {
                            float o = obj[idx];
                            op_s += (o - 1.0f) * (o - 1.0f);
                        }
                    }
                }
            }
            if (ce_s != 0.f)  atomicAdd(&sm.p1.sacc[0], ce_s);
            if (loc_s != 0.f) atomicAdd(&sm.p1.sacc[1], loc_s);
            if (op_s != 0.f)  atomicAdd(&sm.p1.sacc[2], op_s);
        }

        __syncthreads();
        if (t == 0) {
            cpart[n * MBLK + bx] = sm.p1.bcnt;
            float* pa = pacc + ((size_t)n * MBLK + bx) * 3;
            pa[0] = sm.p1.sacc[0]; pa[1] = sm.p1.sacc[1]; pa[2] = sm.p1.sacc[2];
        }
        if (t < MM) {
            unsigned long long r = u64max(u64max(sm.p1.wk[0][t], sm.p1.wk[1][t]),
                                          u64max(sm.p1.wk[2][t], sm.p1.wk[3][t]));
            bkeyp[((size_t)n * MBLK + bx) * MM + t] = r;
        }
    }

    grid.sync();   // all phase-1 writes visible grid-wide

    // ================= PHASE 2: 32 finisher blocks =================
    const int fb = n * MBLK + bx;
    if (fb >= NB) return;
    const int img = fb;
    float* v = val + (size_t)img * PP;
    const float4* v4 = (const float4*)v;
    const int N4 = PP / 4;

    if (t < 3) sm.p2.sacc[t] = 0.f;
    if (t == 0) { sm.p2.nnew = 0; sm.p2.nat = 0; }
    __syncthreads();

    if (t < MM) {
        const unsigned long long* bp = bkeyp + (size_t)img * MBLK * MM + t;
        unsigned long long r = 0ULL;
#pragma unroll
        for (int s = 0; s < MBLK; s++) r = u64max(r, bp[(size_t)s * MM]);
        sm.p2.fl[t] = ~(unsigned)(r & 0xFFFFFFFFULL);
    }
    if (t < MBLK) atomicAdd(&sm.p2.nat, cpart[img * MBLK + t]);
    __syncthreads();

    float d_ce = 0.f, d_loc = 0.f;
    if (t < MM) {
        unsigned p = sm.p2.fl[t];
        bool owner = true;
        for (int j = t + 1; j < MM; j++) if (sm.p2.fl[j] == p) owner = false;
        if (owner) {
            size_t idx = (size_t)img * PP + p;
            bool natPos = (posbit[img * PPW + (p >> 5)] >> (p & 31)) & 1u;
            if (natPos) {
                int bmn = (int)m8[idx];
                if (bmn != t) {
                    const float* row = pred_cls + idx * NCLS;
                    d_ce = row[labels[img * MM + bmn]] - row[labels[img * MM + t]];
                    float4 pb = *(const float4*)(priors + (size_t)p * 4);
                    float4 pd = *(const float4*)(pred_boxes + idx * 4);
                    const float* bf = boxes + ((size_t)img * MM + t) * 4;
                    const float* bn = boxes + ((size_t)img * MM + bmn) * 4;
                    d_loc = locv(pd, pb, bf[0], bf[1], bf[2], bf[3])
                          - locv(pd, pb, bn[0], bn[1], bn[2], bn[3]);
                }
            } else {
                int ix = atomicAdd(&sm.p2.nnew, 1);
                sm.p2.newlist[ix] = ((int)p << 5) | t;
                v[p] = 0.f;
            }
        }
    }
    if (t < 64) {
#pragma unroll
        for (int d = 1; d < 64; d <<= 1) {
            d_ce += __shfl_xor(d_ce, d);
            d_loc += __shfl_xor(d_loc, d);
        }
        if (t == 0) {
            if (d_ce != 0.f)  atomicAdd(&sm.p2.sacc[0], d_ce);
            if (d_loc != 0.f) atomicAdd(&sm.p2.sacc[1], d_loc);
        }
    }
    if (t < MBLK * 3) atomicAdd(&sm.p2.sacc[t % 3], pacc[(size_t)img * MBLK * 3 + t]);
    __syncthreads();

    const int nn = sm.p2.nnew;
    {
        const int hl = lane & 31;
        float nce = 0.f, nloc = 0.f, nop = 0.f;
        for (int i = wave; i < nn; i += 4) {
            int e = sm.p2.newlist[i];
            int p = e >> 5, bm = e & 31;
            size_t idx = (size_t)img * PP + p;
            const float* row = pred_cls + idx * NCLS;
            bool al = lane < 32;
            float a = al ? row[hl] : -INFINITY;
            float b = al ? row[hl + 32] : -INFINITY;
            float c = (al && hl < NCLS - 64) ? row[hl + 64] : -INFINITY;
            float mx = fmaxf(fmaxf(a, b), c);
#pragma unroll
            for (int d = 1; d < 32; d <<= 1) mx = fmaxf(mx, __shfl_xor(mx, d));
            float se = al ? (expf(a - mx) + expf(b - mx)
                             + ((hl < NCLS - 64) ? expf(c - mx) : 0.f)) : 0.f;
#pragma unroll
            for (int d = 1; d < 32; d <<= 1) se += __shfl_xor(se, d);
            if (lane == 0) {
                nce += mx + logf(se) - row[labels[img * MM + bm]];
            } else if (lane == 1) {
                float4 pb = *(const float4*)(priors + (size_t)p * 4);
                float4 pd = *(const float4*)(pred_boxes + idx * 4);
                const float* bb = boxes + ((size_t)img * MM + bm) * 4;
                nloc += locv(pd, pb, bb[0], bb[1], bb[2], bb[3]);
            } else if (lane == 2) {
                float o = obj[idx];
                nop += (o - 1.0f) * (o - 1.0f);
            }
        }
        if (nce != 0.f)  atomicAdd(&sm.p2.sacc[0], nce);
        if (nloc != 0.f) atomicAdd(&sm.p2.sacc[1], nloc);
        if (nop != 0.f)  atomicAdd(&sm.p2.sacc[2], nop);
    }
    __syncthreads();
    if (t == 0) sm.p2.tot = sm.p2.nat + sm.p2.nnew;
    __syncthreads();
    const int s_tot = sm.p2.tot;
    int k = s_tot * 3; if (k > PP) k = PP;

    float result = 0.f;
    if (k >= PP) {
        float s = 0.f;
        for (int i = t; i < N4; i += 256) {
            float4 q = v4[i]; s += q.x + q.y + q.z + q.w;
        }
#pragma unroll
        for (int d = 32; d > 0; d >>= 1) s += __shfl_down(s, d);
        if ((t & 63) == 0) sm.p2.wred[wave] = s;
        __syncthreads();
        if (t == 0) { for (int i = 0; i < 4; i++) result += sm.p2.wred[i]; }
    } else if (k > 0) {
        for (int i = t; i < HB; i += 256) sm.p2.hist[i] = 0;
        if (t == 0) sm.p2.s_c = 0;
        __syncthreads();

        for (int i = t; i < N4; i += 256) {
            float4 q = v4[i];
            atomicAdd(&sm.p2.hist[__float_as_uint(q.x) >> BSH], 1u);
            atomicAdd(&sm.p2.hist[__float_as_uint(q.y) >> BSH], 1u);
            atomicAdd(&sm.p2.hist[__float_as_uint(q.z) >> BSH], 1u);
            atomicAdd(&sm.p2.hist[__float_as_uint(q.w) >> BSH], 1u);
        }
        __syncthreads();

        // descending chunked prefix: thread t owns bins [4095-16t-15 .. 4095-16t]
        unsigned csum = 0;
#pragma unroll
        for (int j = 0; j < 16; j++) csum += sm.p2.hist[4095 - 16 * t - j];
        sm.p2.ssc[t] = csum; __syncthreads();
        for (int off = 1; off < 256; off <<= 1) {
            unsigned x = (t >= off) ? sm.p2.ssc[t - off] : 0u;
            __syncthreads(); sm.p2.ssc[t] += x; __syncthreads();
        }
        unsigned incl = sm.p2.ssc[t], excl = incl - csum;
        if (excl < (unsigned)k && incl >= (unsigned)k) {
            unsigned cum = excl;
#pragma unroll
            for (int j = 0; j < 16; j++) {
                int b = 4095 - 16 * t - j; unsigned h = sm.p2.hist[b];
                if (cum + h >= (unsigned)k) {
                    sm.p2.s_d = b; sm.p2.s_rem = (int)((unsigned)k - cum); break;
                }
                cum += h;
            }
        }
        __syncthreads();
        const int d = sm.p2.s_d; const int rem0 = sm.p2.s_rem;

        float ms = 0.f;
        for (int i = t; i < N4; i += 256) {
            float4 q = v4[i];
#define HND(C) { unsigned b = __float_as_uint(C); int bn = (int)(b >> BSH); \
            if (bn > d) ms += (C); \
            else if (bn == d) { int ix = atomicAdd(&sm.p2.s_c, 1); \
                                if (ix < CAPL) sm.p2.cand[ix] = b; } }
            HND(q.x) HND(q.y) HND(q.z) HND(q.w)
#undef HND
        }
        __syncthreads();
        const int C = sm.p2.s_c;
        const bool okl = (C <= CAPL);

        unsigned cur = (unsigned)d << BSH; int rem = rem0;
        const int shs[3] = {11, 4, 0};
        const int wbs[3] = {7, 7, 4};
        for (int ps = 0; ps < 3; ps++) {
            const int sh = shs[ps], wb = wbs[ps], W = 1 << wb;
            if (t < W) sm.p2.rh[t] = 0;
            __syncthreads();
            if (okl) {
                for (int i = t; i < C; i += 256) {
                    unsigned b = sm.p2.cand[i];
                    if ((b >> (sh + wb)) == (cur >> (sh + wb)))
                        atomicAdd(&sm.p2.rh[(b >> sh) & (W - 1)], 1u);
                }
            } else {
                for (int i = t; i < PP; i += 256) {
                    unsigned b = __float_as_uint(v[i]);
                    if ((b >> (sh + wb)) == (cur >> (sh + wb)))
                        atomicAdd(&sm.p2.rh[(b >> sh) & (W - 1)], 1u);
                }
            }
            __syncthreads();
            if (t == 0) {
                unsigned cum = 0; int dd;
                for (dd = W - 1; dd > 0; --dd) {
                    unsigned h = sm.p2.rh[dd];
                    if (cum + h >= (unsigned)rem) break;
                    cum += h;
                }
                sm.p2.s_cur = cur | ((unsigned)dd << sh);
                sm.p2.s_rr = rem - (int)cum;
            }
            __syncthreads();
            cur = sm.p2.s_cur; rem = sm.p2.s_rr;
            __syncthreads();
        }
        const unsigned thr = cur;
        const float thrv = __uint_as_float(thr);

        float sg = ms, cg = 0.f;
        if (okl) {
            for (int i = t; i < C; i += 256) {
                unsigned b = sm.p2.cand[i];
                if (b > thr) { sg += __uint_as_float(b); cg += 1.f; }
            }
        } else {
            for (int i = t; i < PP; i += 256) {
                unsigned b = __float_as_uint(v[i]);
                if ((int)(b >> BSH) == d && b > thr) { sg += __uint_as_float(b); cg += 1.f; }
            }
        }
#pragma unroll
        for (int dd = 32; dd > 0; dd >>= 1) {
            sg += __shfl_down(sg, dd);
            cg += __shfl_down(cg, dd);
        }
        if ((t & 63) == 0) { sm.p2.wred[wave] = sg; sm.p2.wred2[wave] = cg; }
        __syncthreads();
        if (t == 0) {
            float S = 0.f, Cc = 0.f;
            for (int i = 0; i < 4; i++) { S += sm.p2.wred[i]; Cc += sm.p2.wred2[i]; }
            result = S + ((float)rem0 - Cc) * thrv;
        }
    }

    // last of 32 finisher blocks computes the scalar
    if (t == 0) {
        pcnt[img] = s_tot;
        iacc[img] = make_float4(sm.p2.sacc[0], sm.p2.sacc[1], sm.p2.sacc[2], result);
        __threadfence();
        int old = atomicAdd(done, 1);
        if (old == NB - 1) {
            int np = 0, den = 0; float ce = 0.f, lc = 0.f, op = 0.f, hs = 0.f;
            for (int i = 0; i < NB; i++) {
                int c = pcnt[i];
                np += c;
                int kk = c * 3; if (kk > PP) kk = PP;
                den += kk;
                float4 a = iacc[i];
                ce += a.x; lc += a.y; op += a.z; hs += a.w;
            }
            float npf = (float)np;
            out[0] = ce / npf + op / npf
                   + hs / fmaxf((float)den, 1.0f)
                   + lc / (npf * 4.0f);
        }
    }
}

extern "C" void kernel_launch(void* const* d_in, const int* in_sizes, int n_in,
                              void* d_out, int out_size, void* d_ws, size_t ws_size,
                              hipStream_t stream) {
    const float* pred_boxes = (const float*)d_in[0];
    const float* pred_cls   = (const float*)d_in[1];
    const float* pred_obj   = (const float*)d_in[2];
    const float* priors     = (const float*)d_in[3];
    const float* boxes      = (const float*)d_in[4];
    const int*   labels     = (const int*)d_in[5];

    char* ws = (char*)d_ws;
    int* done  = (int*)(ws + WS_DONE);
    int* pcnt  = (int*)(ws + WS_PCNT);
    float4* iacc = (float4*)(ws + WS_IACC);
    float* pacc = (float*)(ws + WS_PACC);
    int* cpart = (int*)(ws + WS_CPART);
    unsigned long long* bkeyp = (unsigned long long*)(ws + WS_BKEYP);
    unsigned* posbit = (unsigned*)(ws + WS_POSBIT);
    unsigned char* m8 = (unsigned char*)(ws + WS_M8);
    float* val = (float*)(ws + WS_VAL);
    float* out = (float*)d_out;

    void* args[] = {
        (void*)&priors, (void*)&boxes, (void*)&pred_obj, (void*)&pred_boxes,
        (void*)&pred_cls, (void*)&labels, (void*)&bkeyp, (void*)&posbit,
        (void*)&m8, (void*)&val, (void*)&cpart, (void*)&pacc,
        (void*)&pcnt, (void*)&iacc, (void*)&done, (void*)&out
    };
    hipLaunchCooperativeKernel((const void*)k_all, dim3(MBLK, NB), dim3(256),
                               args, 0, stream);
}

// Round 12
// 105.740 us; speedup vs baseline: 1.7370x; 1.7370x over previous
//
#include <hip/hip_runtime.h>
#include <math.h>

#define NB 32
#define PP 24564
#define MM 32
#define NCLS 81
#define CHUNK 1024
#define MBLK 24          // ceil(PP/CHUNK)
#define PPW 768          // posbit u32 words per image
#define BSH 18           // bin = float_bits >> 18 (4096 bins)
#define HB 4096
#define CAPL 2048        // LDS candidate cap (phase 2)

// ---- workspace layout (bytes); counters self-armed in-kernel ----
#define WS_GDONE  0        // int, padded 128B (zeroed by block (0,0) at start)
#define WS_ARR    128      // int[NB] padded: arr[n] at WS_ARR + n*128
#define WS_PCNT   4224     // int[NB]
#define WS_IACC   4352     // float4[NB]
#define WS_PACC   4864     // float[NB*MBLK*3] -> ends 14080
#define WS_CPART  14080    // int[NB*MBLK] -> ends 17152
#define WS_BKEYP  17152    // u64[NB*MBLK*MM] -> ends 213760
#define WS_POSBIT 213760   // u32[NB*PPW] -> ends 312064
#define WS_M8     312064   // u8[NB*PP] -> ends 1098112
#define WS_VAL    1098112  // float[NB*PP], 16B aligned

__device__ __forceinline__ float sl1(float d) {
    float a = fabsf(d);
    return a < 1.0f ? 0.5f * d * d : a - 0.5f;
}
__device__ __forceinline__ unsigned long long u64max(unsigned long long a, unsigned long long b) {
    return a > b ? a : b;
}
__device__ __forceinline__ float locv(const float4& pd, const float4& pb,
                                      float gx1, float gy1, float gx2, float gy2) {
    float pcx = (pb.x + pb.z) * 0.5f, pcy = (pb.y + pb.w) * 0.5f;
    float pw = pb.z - pb.x, ph = pb.w - pb.y;
    float g0 = ((gx1 + gx2) * 0.5f - pcx) / (pw / 10.0f);
    float g1 = ((gy1 + gy2) * 0.5f - pcy) / (ph / 10.0f);
    float g2 = logf((gx2 - gx1) / pw) * 5.0f;
    float g3 = logf((gy2 - gy1) / ph) * 5.0f;
    return sl1(pd.x - g0) + sl1(pd.y - g1) + sl1(pd.z - g2) + sl1(pd.w - g3);
}

union SMem {
    struct {
        float4 spri[CHUNK];                 // 16 KB
        unsigned char sm8[CHUNK];
        float bx0[MM], by0[MM], bx1[MM], by1[MM], bar_[MM];
        unsigned long long wk[4][MM];
        int bcnt;
        float sacc[3];
        int islast;
    } p1;
    struct {
        unsigned hist[HB];                  // 16 KB
        unsigned cand[CAPL];                // 8 KB
        unsigned ssc[256];
        unsigned rh[128];
        unsigned fl[MM];
        int newlist[MM];
        float sacc[3];
        float wred[4], wred2[4];
        int nnew, nat, tot;
        int s_c, s_d, s_rem, s_rr;
        unsigned s_cur;
    } p2;
};

extern "C" __global__ void __launch_bounds__(256) k_all(
    const float* __restrict__ priors,
    const float* __restrict__ boxes,
    const float* __restrict__ obj,
    const float* __restrict__ pred_boxes,
    const float* __restrict__ pred_cls,
    const int* __restrict__ labels,
    unsigned long long* __restrict__ bkeyp,
    unsigned int* __restrict__ posbit,
    unsigned char* __restrict__ m8,
    float* __restrict__ val,
    int* __restrict__ cpart,
    float* __restrict__ pacc,
    int* __restrict__ pcnt,
    float4* __restrict__ iacc,
    int* __restrict__ arr,      // padded: arr[n*32]
    int* __restrict__ gdone,
    float* __restrict__ out)
{
    const int n = blockIdx.y;
    const int bx = blockIdx.x;
    const int t = threadIdx.x;
    const int lane = t & 63;
    const int wave = t >> 6;
    const int p0 = bx * CHUNK;

    __shared__ SMem sm;

    // re-arm counters (any prior value): block (0,n) owns arr[n]; (0,0) owns gdone.
    // all 768 blocks are co-resident (3/CU); exch lands ~20k cycles before any arrival.
    if (bx == 0 && t == 0) {
        atomicExch(&arr[n * 32], 0);
        if (n == 0) atomicExch(gdone, 0);
    }

    // ================= PHASE 1: matching + natural-positive losses =================
    {
        float ov[4];
#pragma unroll
        for (int i = 0; i < 4; i++) {
            int p = p0 + t + i * 256;
            float4 v;
            if (p < PP) { v = *(const float4*)(priors + (size_t)p * 4);
                          ov[i] = obj[(size_t)n * PP + p]; }
            else { v.x = 3.f; v.y = 3.f; v.z = 3.5f; v.w = 3.5f; ov[i] = 0.f; }
            sm.p1.spri[t + i * 256] = v;
        }
        if (t < MM) {
            const float* b = boxes + ((size_t)n * MM + t) * 4;
            float x1 = b[0], y1 = b[1], x2 = b[2], y2 = b[3];
            sm.p1.bx0[t] = x1; sm.p1.by0[t] = y1; sm.p1.bx1[t] = x2; sm.p1.by1[t] = y2;
            sm.p1.bar_[t] = (x2 - x1) * (y2 - y1);
        }
        if (t == 0) sm.p1.bcnt = 0;
        if (t < 3) sm.p1.sacc[t] = 0.f;
        __syncthreads();

        float4 pr0 = sm.p1.spri[t], pr1 = sm.p1.spri[t + 256],
               pr2 = sm.p1.spri[t + 512], pr3 = sm.p1.spri[t + 768];
        const float pa0 = (pr0.z - pr0.x) * (pr0.w - pr0.y);
        const float pa1 = (pr1.z - pr1.x) * (pr1.w - pr1.y);
        const float pa2 = (pr2.z - pr2.x) * (pr2.w - pr2.y);
        const float pa3 = (pr3.z - pr3.x) * (pr3.w - pr3.y);
        unsigned pb0 = 0, pb1 = 0, pb2 = 0, pb3 = 0;

#define DO_IOU(PR, PA, PB, ROFF) { \
        float w = fminf(x1, PR.z) - fmaxf(x0, PR.x); \
        float h = fminf(y1, PR.w) - fmaxf(y0, PR.y); \
        w = fmaxf(w, 0.0f); h = fmaxf(h, 0.0f); \
        float inter = w * h; \
        float iou = inter / (ar + PA - inter); \
        unsigned ib = __float_as_uint(iou); \
        unsigned nk = (ib & 0xFFFFFFE0u) | (unsigned)(31 - m); \
        PB = PB > nk ? PB : nk; \
        unsigned long long kk = ((unsigned long long)ib << 32) \
            | (unsigned long long)(0xFFFFFFFFu - (unsigned)(p0 + t + (ROFF))); \
        km = u64max(km, kk); }

#pragma unroll 2
        for (int m = 0; m < MM; m++) {
            const float x0 = sm.p1.bx0[m], y0 = sm.p1.by0[m],
                        x1 = sm.p1.bx1[m], y1 = sm.p1.by1[m], ar = sm.p1.bar_[m];
            unsigned long long km = 0ULL;
            DO_IOU(pr0, pa0, pb0, 0)
            DO_IOU(pr1, pa1, pb1, 256)
            DO_IOU(pr2, pa2, pb2, 512)
            DO_IOU(pr3, pa3, pb3, 768)
#pragma unroll
            for (int d = 1; d < 64; d <<= 1)
                km = u64max(km, (unsigned long long)__shfl_xor(km, d));
            if (lane == 0) sm.p1.wk[wave][m] = km;
        }
#undef DO_IOU

        int cnt = 0;
        unsigned long long bl[4];
#define ROWOUT(PB, R) { \
        int p = p0 + t + (R) * 256; \
        bool pos = (PB >= 0x3F000000u) && (p < PP); \
        unsigned long long ball = __ballot(pos); \
        bl[R] = ball; \
        unsigned char mb = (unsigned char)(31u - (PB & 31u)); \
        sm.p1.sm8[t + (R) * 256] = mb; \
        if (lane == 0) { \
            int wi = n * PPW + ((p0 + (R) * 256 + wave * 64) >> 5); \
            posbit[wi] = (unsigned)ball; posbit[wi + 1] = (unsigned)(ball >> 32); \
            cnt += __popcll(ball); \
        } \
        if (p < PP) { \
            size_t idx = (size_t)n * PP + p; \
            m8[idx] = mb; \
            val[idx] = pos ? 0.f : ov[R] * ov[R]; \
        } }
        ROWOUT(pb0, 0) ROWOUT(pb1, 1) ROWOUT(pb2, 2) ROWOUT(pb3, 3)
#undef ROWOUT
        if (lane == 0 && cnt) atomicAdd(&sm.p1.bcnt, cnt);

        {
            const int half = lane >> 5, hl = lane & 31;
            float ce_s = 0.f, loc_s = 0.f, op_s = 0.f;
#pragma unroll
            for (int R = 0; R < 4; R++) {
                unsigned long long mask = bl[R];
                const int roff = R * 256 + wave * 64;
                while (mask) {
                    int i1 = __ffsll((long long)mask) - 1; mask &= mask - 1;
                    int i2 = -1;
                    if (mask) { i2 = __ffsll((long long)mask) - 1; mask &= mask - 1; }
                    const int pi = half ? i2 : i1;
                    const bool act = pi >= 0;
                    const int poff = roff + (act ? pi : 0);
                    const size_t idx = (size_t)n * PP + p0 + poff;

                    const int bm = sm.p1.sm8[poff];
                    const float* row = pred_cls + idx * NCLS;
                    float a = act ? row[hl] : -INFINITY;
                    float b = act ? row[hl + 32] : -INFINITY;
                    float c = (act && hl < NCLS - 64) ? row[hl + 64] : -INFINITY;
                    float mx = fmaxf(fmaxf(a, b), c);
#pragma unroll
                    for (int d = 1; d < 32; d <<= 1) mx = fmaxf(mx, __shfl_xor(mx, d));
                    float se = act ? (expf(a - mx) + expf(b - mx)
                                      + ((hl < NCLS - 64) ? expf(c - mx) : 0.f)) : 0.f;
#pragma unroll
                    for (int d = 1; d < 32; d <<= 1) se += __shfl_xor(se, d);

                    if (act) {
                        if (hl == 0) {
                            ce_s += mx + logf(se) - row[labels[n * MM + bm]];
                        } else if (hl == 1) {
                            float4 pb = sm.p1.spri[poff];
                            float4 pd = *(const float4*)(pred_boxes + idx * 4);
                            loc_s += locv(pd, pb, sm.p1.bx0[bm], sm.p1.by0[bm],
                                          sm.p1.bx1[bm], sm.p1.by1[bm]);
                        } else if (hl == 2) {
                            float o = obj[idx];
                            op_s += (o - 1.0f) * (o - 1.0f);
                        }
                    }
                }
            }
            if (ce_s != 0.f)  atomicAdd(&sm.p1.sacc[0], ce_s);
            if (loc_s != 0.f) atomicAdd(&sm.p1.sacc[1], loc_s);
            if (op_s != 0.f)  atomicAdd(&sm.p1.sacc[2], op_s);
        }

        __syncthreads();
        if (t == 0) {
            cpart[n * MBLK + bx] = sm.p1.bcnt;
            float* pa = pacc + ((size_t)n * MBLK + bx) * 3;
            pa[0] = sm.p1.sacc[0]; pa[1] = sm.p1.sacc[1]; pa[2] = sm.p1.sacc[2];
        }
        if (t < MM) {
            unsigned long long r = u64max(u64max(sm.p1.wk[0][t], sm.p1.wk[1][t]),
                                          u64max(sm.p1.wk[2][t], sm.p1.wk[3][t]));
            bkeyp[((size_t)n * MBLK + bx) * MM + t] = r;
        }
    }

    // ---- per-image arrival: last of 24 blocks becomes image n's finisher ----
    __syncthreads();           // drains all this block's global stores (vmcnt 0)
    if (t == 0) {
        __threadfence();       // device-scope release of this block's writes
        int old = atomicAdd(&arr[n * 32], 1);
        sm.p1.islast = (old == MBLK - 1);
    }
    __syncthreads();
    if (!sm.p1.islast) return;
    if (t == 0) __threadfence();   // acquire: see sibling blocks' writes
    __syncthreads();

    // ================= PHASE 2: finisher for image n =================
    const int img = n;
    float* v = val + (size_t)img * PP;
    const float4* v4 = (const float4*)v;
    const int N4 = PP / 4;

    if (t < 3) sm.p2.sacc[t] = 0.f;
    if (t == 0) { sm.p2.nnew = 0; sm.p2.nat = 0; }
    __syncthreads();

    if (t < MM) {
        const unsigned long long* bp = bkeyp + (size_t)img * MBLK * MM + t;
        unsigned long long r = 0ULL;
#pragma unroll
        for (int s = 0; s < MBLK; s++) r = u64max(r, bp[(size_t)s * MM]);
        sm.p2.fl[t] = ~(unsigned)(r & 0xFFFFFFFFULL);
    }
    if (t < MBLK) atomicAdd(&sm.p2.nat, cpart[img * MBLK + t]);
    __syncthreads();

    float d_ce = 0.f, d_loc = 0.f;
    if (t < MM) {
        unsigned p = sm.p2.fl[t];
        bool owner = true;
        for (int j = t + 1; j < MM; j++) if (sm.p2.fl[j] == p) owner = false;
        if (owner) {
            size_t idx = (size_t)img * PP + p;
            bool natPos = (posbit[img * PPW + (p >> 5)] >> (p & 31)) & 1u;
            if (natPos) {
                int bmn = (int)m8[idx];
                if (bmn != t) {
                    const float* row = pred_cls + idx * NCLS;
                    d_ce = row[labels[img * MM + bmn]] - row[labels[img * MM + t]];
                    float4 pb = *(const float4*)(priors + (size_t)p * 4);
                    float4 pd = *(const float4*)(pred_boxes + idx * 4);
                    const float* bf = boxes + ((size_t)img * MM + t) * 4;
                    const float* bn = boxes + ((size_t)img * MM + bmn) * 4;
                    d_loc = locv(pd, pb, bf[0], bf[1], bf[2], bf[3])
                          - locv(pd, pb, bn[0], bn[1], bn[2], bn[3]);
                }
            } else {
                int ix = atomicAdd(&sm.p2.nnew, 1);
                sm.p2.newlist[ix] = ((int)p << 5) | t;
                v[p] = 0.f;
            }
        }
    }
    if (t < 64) {
#pragma unroll
        for (int d = 1; d < 64; d <<= 1) {
            d_ce += __shfl_xor(d_ce, d);
            d_loc += __shfl_xor(d_loc, d);
        }
        if (t == 0) {
            if (d_ce != 0.f)  atomicAdd(&sm.p2.sacc[0], d_ce);
            if (d_loc != 0.f) atomicAdd(&sm.p2.sacc[1], d_loc);
        }
    }
    if (t < MBLK * 3) atomicAdd(&sm.p2.sacc[t % 3], pacc[(size_t)img * MBLK * 3 + t]);
    __syncthreads();

    const int nn = sm.p2.nnew;
    {
        const int hl = lane & 31;
        float nce = 0.f, nloc = 0.f, nop = 0.f;
        for (int i = wave; i < nn; i += 4) {
            int e = sm.p2.newlist[i];
            int p = e >> 5, bm = e & 31;
            size_t idx = (size_t)img * PP + p;
            const float* row = pred_cls + idx * NCLS;
            bool al = lane < 32;
            float a = al ? row[hl] : -INFINITY;
            float b = al ? row[hl + 32] : -INFINITY;
            float c = (al && hl < NCLS - 64) ? row[hl + 64] : -INFINITY;
            float mx = fmaxf(fmaxf(a, b), c);
#pragma unroll
            for (int d = 1; d < 32; d <<= 1) mx = fmaxf(mx, __shfl_xor(mx, d));
            float se = al ? (expf(a - mx) + expf(b - mx)
                             + ((hl < NCLS - 64) ? expf(c - mx) : 0.f)) : 0.f;
#pragma unroll
            for (int d = 1; d < 32; d <<= 1) se += __shfl_xor(se, d);
            if (lane == 0) {
                nce += mx + logf(se) - row[labels[img * MM + bm]];
            } else if (lane == 1) {
                float4 pb = *(const float4*)(priors + (size_t)p * 4);
                float4 pd = *(const float4*)(pred_boxes + idx * 4);
                const float* bb = boxes + ((size_t)img * MM + bm) * 4;
                nloc += locv(pd, pb, bb[0], bb[1], bb[2], bb[3]);
            } else if (lane == 2) {
                float o = obj[idx];
                nop += (o - 1.0f) * (o - 1.0f);
            }
        }
        if (nce != 0.f)  atomicAdd(&sm.p2.sacc[0], nce);
        if (nloc != 0.f) atomicAdd(&sm.p2.sacc[1], nloc);
        if (nop != 0.f)  atomicAdd(&sm.p2.sacc[2], nop);
    }
    __syncthreads();
    if (t == 0) sm.p2.tot = sm.p2.nat + sm.p2.nnew;
    __syncthreads();
    const int s_tot = sm.p2.tot;
    int k = s_tot * 3; if (k > PP) k = PP;

    float result = 0.f;
    if (k >= PP) {
        float s = 0.f;
        for (int i = t; i < N4; i += 256) {
            float4 q = v4[i]; s += q.x + q.y + q.z + q.w;
        }
#pragma unroll
        for (int d = 32; d > 0; d >>= 1) s += __shfl_down(s, d);
        if ((t & 63) == 0) sm.p2.wred[wave] = s;
        __syncthreads();
        if (t == 0) { for (int i = 0; i < 4; i++) result += sm.p2.wred[i]; }
    } else if (k > 0) {
        for (int i = t; i < HB; i += 256) sm.p2.hist[i] = 0;
        if (t == 0) sm.p2.s_c = 0;
        __syncthreads();

        for (int i = t; i < N4; i += 256) {
            float4 q = v4[i];
            atomicAdd(&sm.p2.hist[__float_as_uint(q.x) >> BSH], 1u);
            atomicAdd(&sm.p2.hist[__float_as_uint(q.y) >> BSH], 1u);
            atomicAdd(&sm.p2.hist[__float_as_uint(q.z) >> BSH], 1u);
            atomicAdd(&sm.p2.hist[__float_as_uint(q.w) >> BSH], 1u);
        }
        __syncthreads();

        unsigned csum = 0;
#pragma unroll
        for (int j = 0; j < 16; j++) csum += sm.p2.hist[4095 - 16 * t - j];
        sm.p2.ssc[t] = csum; __syncthreads();
        for (int off = 1; off < 256; off <<= 1) {
            unsigned x = (t >= off) ? sm.p2.ssc[t - off] : 0u;
            __syncthreads(); sm.p2.ssc[t] += x; __syncthreads();
        }
        unsigned incl = sm.p2.ssc[t], excl = incl - csum;
        if (excl < (unsigned)k && incl >= (unsigned)k) {
            unsigned cum = excl;
#pragma unroll
            for (int j = 0; j < 16; j++) {
                int b = 4095 - 16 * t - j; unsigned h = sm.p2.hist[b];
                if (cum + h >= (unsigned)k) {
                    sm.p2.s_d = b; sm.p2.s_rem = (int)((unsigned)k - cum); break;
                }
                cum += h;
            }
        }
        __syncthreads();
        const int d = sm.p2.s_d; const int rem0 = sm.p2.s_rem;

        float ms = 0.f;
        for (int i = t; i < N4; i += 256) {
            float4 q = v4[i];
#define HND(C) { unsigned b = __float_as_uint(C); int bn = (int)(b >> BSH); \
            if (bn > d) ms += (C); \
            else if (bn == d) { int ix = atomicAdd(&sm.p2.s_c, 1); \
                                if (ix < CAPL) sm.p2.cand[ix] = b; } }
            HND(q.x) HND(q.y) HND(q.z) HND(q.w)
#undef HND
        }
        __syncthreads();
        const int C = sm.p2.s_c;
        const bool okl = (C <= CAPL);

        unsigned cur = (unsigned)d << BSH; int rem = rem0;
        const int shs[3] = {11, 4, 0};
        const int wbs[3] = {7, 7, 4};
        for (int ps = 0; ps < 3; ps++) {
            const int sh = shs[ps], wb = wbs[ps], W = 1 << wb;
            if (t < W) sm.p2.rh[t] = 0;
            __syncthreads();
            if (okl) {
                for (int i = t; i < C; i += 256) {
                    unsigned b = sm.p2.cand[i];
                    if ((b >> (sh + wb)) == (cur >> (sh + wb)))
                        atomicAdd(&sm.p2.rh[(b >> sh) & (W - 1)], 1u);
                }
            } else {
                for (int i = t; i < PP; i += 256) {
                    unsigned b = __float_as_uint(v[i]);
                    if ((b >> (sh + wb)) == (cur >> (sh + wb)))
                        atomicAdd(&sm.p2.rh[(b >> sh) & (W - 1)], 1u);
                }
            }
            __syncthreads();
            if (t == 0) {
                unsigned cum = 0; int dd;
                for (dd = W - 1; dd > 0; --dd) {
                    unsigned h = sm.p2.rh[dd];
                    if (cum + h >= (unsigned)rem) break;
                    cum += h;
                }
                sm.p2.s_cur = cur | ((unsigned)dd << sh);
                sm.p2.s_rr = rem - (int)cum;
            }
            __syncthreads();
            cur = sm.p2.s_cur; rem = sm.p2.s_rr;
            __syncthreads();
        }
        const unsigned thr = cur;
        const float thrv = __uint_as_float(thr);

        float sg = ms, cg = 0.f;
        if (okl) {
            for (int i = t; i < C; i += 256) {
                unsigned b = sm.p2.cand[i];
                if (b > thr) { sg += __uint_as_float(b); cg += 1.f; }
            }
        } else {
            for (int i = t; i < PP; i += 256) {
                unsigned b = __float_as_uint(v[i]);
                if ((int)(b >> BSH) == d && b > thr) { sg += __uint_as_float(b); cg += 1.f; }
            }
        }
#pragma unroll
        for (int dd = 32; dd > 0; dd >>= 1) {
            sg += __shfl_down(sg, dd);
            cg += __shfl_down(cg, dd);
        }
        if ((t & 63) == 0) { sm.p2.wred[wave] = sg; sm.p2.wred2[wave] = cg; }
        __syncthreads();
        if (t == 0) {
            float S = 0.f, Cc = 0.f;
            for (int i = 0; i < 4; i++) { S += sm.p2.wred[i]; Cc += sm.p2.wred2[i]; }
            result = S + ((float)rem0 - Cc) * thrv;
        }
    }

    // ---- last of the 32 image-finishers computes the scalar ----
    if (t == 0) {
        pcnt[img] = s_tot;
        iacc[img] = make_float4(sm.p2.sacc[0], sm.p2.sacc[1], sm.p2.sacc[2], result);
        __threadfence();
        int old = atomicAdd(gdone, 1);
        if (old == NB - 1) {
            __threadfence();
            int np = 0, den = 0; float ce = 0.f, lc = 0.f, op = 0.f, hs = 0.f;
            for (int i = 0; i < NB; i++) {
                int c = pcnt[i];
                np += c;
                int kk = c * 3; if (kk > PP) kk = PP;
                den += kk;
                float4 a = iacc[i];
                ce += a.x; lc += a.y; op += a.z; hs += a.w;
            }
            float npf = (float)np;
            out[0] = ce / npf + op / npf
                   + hs / fmaxf((float)den, 1.0f)
                   + lc / (npf * 4.0f);
        }
    }
}

extern "C" void kernel_launch(void* const* d_in, const int* in_sizes, int n_in,
                              void* d_out, int out_size, void* d_ws, size_t ws_size,
                              hipStream_t stream) {
    const float* pred_boxes = (const float*)d_in[0];
    const float* pred_cls   = (const float*)d_in[1];
    const float* pred_obj   = (const float*)d_in[2];
    const float* priors     = (const float*)d_in[3];
    const float* boxes      = (const float*)d_in[4];
    const int*   labels     = (const int*)d_in[5];

    char* ws = (char*)d_ws;
    int* gdone = (int*)(ws + WS_GDONE);
    int* arr   = (int*)(ws + WS_ARR);
    int* pcnt  = (int*)(ws + WS_PCNT);
    float4* iacc = (float4*)(ws + WS_IACC);
    float* pacc = (float*)(ws + WS_PACC);
    int* cpart = (int*)(ws + WS_CPART);
    unsigned long long* bkeyp = (unsigned long long*)(ws + WS_BKEYP);
    unsigned* posbit = (unsigned*)(ws + WS_POSBIT);
    unsigned char* m8 = (unsigned char*)(ws + WS_M8);
    float* val = (float*)(ws + WS_VAL);

    k_all<<<dim3(MBLK, NB), 256, 0, stream>>>(priors, boxes, pred_obj, pred_boxes,
                                              pred_cls, labels, bkeyp, posbit, m8,
                                              val, cpart, pacc, pcnt, iacc,
                                              arr, gdone, (float*)d_out);
}

// Round 13
// 78.510 us; speedup vs baseline: 2.3395x; 1.3468x over previous
//
#include <hip/hip_runtime.h>
#include <math.h>

#define NB 32
#define PP 24564
#define MM 32
#define NCLS 81
#define CHUNK 1024
#define MBLK 24          // ceil(PP/CHUNK)
#define PPW 768          // posbit u32 words per image
#define BSH 18           // bin = float_bits >> 18 (4096 bins)
#define HB 4096
#define CAPL 2048        // LDS candidate cap in k_fin

// ---- workspace layout (bytes); nothing pre-zeroed by host ----
#define WS_DONE   0        // int (zeroed by k_match block (0,0))
#define WS_PCNT   32       // int[NB] (k_fin writes)
#define WS_IACC   160      // float4[NB]: {ce,loc,op,hn} (k_fin writes)
#define WS_PACC   672      // float[NB*MBLK*3] (k_match plain stores) -> ends 9888
#define WS_CPART  9888     // int[NB*MBLK] (k_match plain stores) -> ends 12960
#define WS_BKEYP  12960    // u64[NB*MBLK*MM] -> ends 209568
#define WS_POSBIT 209568   // u32[NB*PPW] -> ends 307872
#define WS_M8     307872   // u8[NB*PP] -> ends 1093920
#define WS_VAL    1093936  // float[NB*PP] 16B-aligned

__device__ __forceinline__ float sl1(float d) {
    float a = fabsf(d);
    return a < 1.0f ? 0.5f * d * d : a - 0.5f;
}
__device__ __forceinline__ unsigned long long u64max(unsigned long long a, unsigned long long b) {
    return a > b ? a : b;
}
__device__ __forceinline__ float locv(const float4& pd, const float4& pb,
                                      float gx1, float gy1, float gx2, float gy2) {
    float pcx = (pb.x + pb.z) * 0.5f, pcy = (pb.y + pb.w) * 0.5f;
    float pw = pb.z - pb.x, ph = pb.w - pb.y;
    float g0 = ((gx1 + gx2) * 0.5f - pcx) / (pw / 10.0f);
    float g1 = ((gy1 + gy2) * 0.5f - pcy) / (ph / 10.0f);
    float g2 = logf((gx2 - gx1) / pw) * 5.0f;
    float g3 = logf((gy2 - gy1) / ph) * 5.0f;
    return sl1(pd.x - g0) + sl1(pd.y - g1) + sl1(pd.z - g2) + sl1(pd.w - g3);
}

// ---------- matching + natural-positive losses fused ----------
extern "C" __global__ void __launch_bounds__(256) k_match(
    const float* __restrict__ priors,
    const float* __restrict__ boxes,
    const float* __restrict__ obj,
    const float* __restrict__ pred_boxes,
    const float* __restrict__ pred_cls,
    const int* __restrict__ labels,
    unsigned long long* __restrict__ bkeyp,
    unsigned int* __restrict__ posbit,
    unsigned char* __restrict__ m8,
    float* __restrict__ val,
    int* __restrict__ cpart,
    float* __restrict__ pacc,
    int* __restrict__ done)
{
    const int n = blockIdx.y;
    const int t = threadIdx.x;
    const int lane = t & 63;
    const int wave = t >> 6;
    const int bx = blockIdx.x;
    const int p0 = bx * CHUNK;

    if (bx == 0 && n == 0 && t == 0) *done = 0;

    __shared__ unsigned char sm8[CHUNK];
    __shared__ float bx0[MM], by0[MM], bx1[MM], by1[MM], bar_[MM];
    __shared__ unsigned long long wk[4][MM];
    __shared__ int bcnt;
    __shared__ float sacc[3];

    // priors directly into registers (coalesced float4); dummy for OOB (iou=0)
    float4 pr0, pr1, pr2, pr3;
    float ov[4];
    {
        const float4 dummy = make_float4(3.f, 3.f, 3.5f, 3.5f);
        int p;
        p = p0 + t;        if (p < PP) { pr0 = *(const float4*)(priors + (size_t)p * 4); ov[0] = obj[(size_t)n * PP + p]; } else { pr0 = dummy; ov[0] = 0.f; }
        p = p0 + t + 256;  if (p < PP) { pr1 = *(const float4*)(priors + (size_t)p * 4); ov[1] = obj[(size_t)n * PP + p]; } else { pr1 = dummy; ov[1] = 0.f; }
        p = p0 + t + 512;  if (p < PP) { pr2 = *(const float4*)(priors + (size_t)p * 4); ov[2] = obj[(size_t)n * PP + p]; } else { pr2 = dummy; ov[2] = 0.f; }
        p = p0 + t + 768;  if (p < PP) { pr3 = *(const float4*)(priors + (size_t)p * 4); ov[3] = obj[(size_t)n * PP + p]; } else { pr3 = dummy; ov[3] = 0.f; }
    }
    if (t < MM) {
        const float* b = boxes + ((size_t)n * MM + t) * 4;
        float x1 = b[0], y1 = b[1], x2 = b[2], y2 = b[3];
        bx0[t] = x1; by0[t] = y1; bx1[t] = x2; by1[t] = y2;
        bar_[t] = (x2 - x1) * (y2 - y1);
    }
    if (t == 0) bcnt = 0;
    if (t < 3) sacc[t] = 0.f;
    __syncthreads();

    const float pa0 = (pr0.z - pr0.x) * (pr0.w - pr0.y);
    const float pa1 = (pr1.z - pr1.x) * (pr1.w - pr1.y);
    const float pa2 = (pr2.z - pr2.x) * (pr2.w - pr2.y);
    const float pa3 = (pr3.z - pr3.x) * (pr3.w - pr3.y);
    unsigned pb0 = 0, pb1 = 0, pb2 = 0, pb3 = 0;   // per-prior keys: trunc-iou | (31-m)

    // fast rcp instead of IEEE div: 1-ulp error, internally consistent everywhere
#define DO_IOU(PR, PA, PB, ROFF) { \
        float w = fminf(x1, PR.z) - fmaxf(x0, PR.x); \
        float h = fminf(y1, PR.w) - fmaxf(y0, PR.y); \
        w = fmaxf(w, 0.0f); h = fmaxf(h, 0.0f); \
        float inter = w * h; \
        float iou = inter * __builtin_amdgcn_rcpf(ar + PA - inter); \
        unsigned ib = __float_as_uint(iou); \
        unsigned nk = (ib & 0xFFFFFFE0u) | (unsigned)(31 - m); \
        PB = PB > nk ? PB : nk; \
        unsigned long long kk = ((unsigned long long)ib << 32) \
            | (unsigned long long)(0xFFFFFFFFu - (unsigned)(p0 + t + (ROFF))); \
        km = u64max(km, kk); }

#pragma unroll 2
    for (int m = 0; m < MM; m++) {
        const float x0 = bx0[m], y0 = by0[m], x1 = bx1[m], y1 = by1[m], ar = bar_[m];
        unsigned long long km = 0ULL;
        DO_IOU(pr0, pa0, pb0, 0)
        DO_IOU(pr1, pa1, pb1, 256)
        DO_IOU(pr2, pa2, pb2, 512)
        DO_IOU(pr3, pa3, pb3, 768)
#pragma unroll
        for (int d = 1; d < 64; d <<= 1)
            km = u64max(km, (unsigned long long)__shfl_xor(km, d));
        if (lane == 0) wk[wave][m] = km;
    }
#undef DO_IOU

    int cnt = 0;
    unsigned long long bl[4];
#define ROWOUT(PB, R) { \
        int p = p0 + t + (R) * 256; \
        bool pos = (PB >= 0x3F000000u) && (p < PP); \
        unsigned long long ball = __ballot(pos); \
        bl[R] = ball; \
        unsigned char mb = (unsigned char)(31u - (PB & 31u)); \
        sm8[t + (R) * 256] = mb; \
        if (lane == 0) { \
            int wi = n * PPW + ((p0 + (R) * 256 + wave * 64) >> 5); \
            posbit[wi] = (unsigned)ball; posbit[wi + 1] = (unsigned)(ball >> 32); \
            cnt += __popcll(ball); \
        } \
        if (p < PP) { \
            size_t idx = (size_t)n * PP + p; \
            m8[idx] = mb; \
            val[idx] = pos ? 0.f : ov[R] * ov[R]; \
        } }
    ROWOUT(pb0, 0) ROWOUT(pb1, 1) ROWOUT(pb2, 2) ROWOUT(pb3, 3)
#undef ROWOUT
    if (lane == 0 && cnt) atomicAdd(&bcnt, cnt);

    // ---- natural-positive losses inline (half-wave per positive) ----
    {
        const int half = lane >> 5, hl = lane & 31;
        float ce_s = 0.f, loc_s = 0.f, op_s = 0.f;
#pragma unroll
        for (int R = 0; R < 4; R++) {
            unsigned long long mask = bl[R];
            const int roff = R * 256 + wave * 64;
            while (mask) {
                int i1 = __ffsll((long long)mask) - 1; mask &= mask - 1;
                int i2 = -1;
                if (mask) { i2 = __ffsll((long long)mask) - 1; mask &= mask - 1; }
                const int pi = half ? i2 : i1;
                const bool act = pi >= 0;
                const int poff = roff + (act ? pi : 0);
                const size_t idx = (size_t)n * PP + p0 + poff;

                const int bm = sm8[poff];
                const float* row = pred_cls + idx * NCLS;
                float a = act ? row[hl] : -INFINITY;
                float b = act ? row[hl + 32] : -INFINITY;
                float c = (act && hl < NCLS - 64) ? row[hl + 64] : -INFINITY;
                float mx = fmaxf(fmaxf(a, b), c);
#pragma unroll
                for (int d = 1; d < 32; d <<= 1) mx = fmaxf(mx, __shfl_xor(mx, d));
                float se = act ? (expf(a - mx) + expf(b - mx)
                                  + ((hl < NCLS - 64) ? expf(c - mx) : 0.f)) : 0.f;
#pragma unroll
                for (int d = 1; d < 32; d <<= 1) se += __shfl_xor(se, d);

                if (act) {
                    if (hl == 0) {
                        ce_s += mx + logf(se) - row[labels[n * MM + bm]];
                    } else if (hl == 1) {
                        float4 pb = *(const float4*)(priors + (size_t)(p0 + poff) * 4);
                        float4 pd = *(const float4*)(pred_boxes + idx * 4);
                        loc_s += locv(pd, pb, bx0[bm], by0[bm], bx1[bm], by1[bm]);
                    } else if (hl == 2) {
                        float o = obj[idx];
                        op_s += (o - 1.0f) * (o - 1.0f);
                    }
                }
            }
        }
        if (ce_s != 0.f)  atomicAdd(&sacc[0], ce_s);
        if (loc_s != 0.f) atomicAdd(&sacc[1], loc_s);
        if (op_s != 0.f)  atomicAdd(&sacc[2], op_s);
    }

    __syncthreads();
    if (t == 0) {
        cpart[n * MBLK + bx] = bcnt;
        float* pa = pacc + ((size_t)n * MBLK + bx) * 3;
        pa[0] = sacc[0]; pa[1] = sacc[1]; pa[2] = sacc[2];
    }
    if (t < MM) {
        unsigned long long r = u64max(u64max(wk[0][t], wk[1][t]),
                                      u64max(wk[2][t], wk[3][t]));
        bkeyp[((size_t)n * MBLK + bx) * MM + t] = r;
    }
}

// ---------- forced fixups + partial-sum + top-k selection + finalize ----------
extern "C" __global__ void __launch_bounds__(512) k_fin(
    const float* __restrict__ priors,
    const float* __restrict__ boxes,
    const float* __restrict__ obj,
    const float* __restrict__ pred_boxes,
    const float* __restrict__ pred_cls,
    const int* __restrict__ labels,
    const unsigned long long* __restrict__ bkeyp,
    const unsigned int* __restrict__ posbit,
    const unsigned char* __restrict__ m8,
    const int* __restrict__ cpart,
    const float* __restrict__ pacc,
    float* __restrict__ val,
    int* __restrict__ pcnt,
    float4* __restrict__ iacc,
    int* __restrict__ done,
    float* __restrict__ out)
{
    const int n = blockIdx.x;
    const int t = threadIdx.x;
    const int lane = t & 63;
    const int wave = t >> 6;
    float* v = val + (size_t)n * PP;
    const float4* v4 = (const float4*)v;
    const int N4 = PP / 4;

    __shared__ unsigned fl[MM];
    __shared__ int newlist[MM];
    __shared__ int s_nnew, s_nat, s_tot;
    __shared__ float sacc[3];
    __shared__ float wred[8], wred2[8];

    if (t < 3) sacc[t] = 0.f;
    if (t == 0) { s_nnew = 0; s_nat = 0; }
    __syncthreads();

    if (t < MM) {
        const unsigned long long* bp = bkeyp + (size_t)n * MBLK * MM + t;
        unsigned long long r = 0ULL;
#pragma unroll
        for (int s = 0; s < MBLK; s++) r = u64max(r, bp[(size_t)s * MM]);
        fl[t] = ~(unsigned)(r & 0xFFFFFFFFULL);
    }
    if (t < MBLK) atomicAdd(&s_nat, cpart[n * MBLK + t]);
    __syncthreads();

    float d_ce = 0.f, d_loc = 0.f;
    if (t < MM) {
        unsigned p = fl[t];
        bool owner = true;
        for (int j = t + 1; j < MM; j++) if (fl[j] == p) owner = false;
        if (owner) {
            size_t idx = (size_t)n * PP + p;
            bool natPos = (posbit[n * PPW + (p >> 5)] >> (p & 31)) & 1u;
            if (natPos) {
                int bmn = (int)m8[idx];
                if (bmn != t) {
                    const float* row = pred_cls + idx * NCLS;
                    d_ce = row[labels[n * MM + bmn]] - row[labels[n * MM + t]];
                    float4 pb = *(const float4*)(priors + (size_t)p * 4);
                    float4 pd = *(const float4*)(pred_boxes + idx * 4);
                    const float* bf = boxes + ((size_t)n * MM + t) * 4;
                    const float* bn = boxes + ((size_t)n * MM + bmn) * 4;
                    d_loc = locv(pd, pb, bf[0], bf[1], bf[2], bf[3])
                          - locv(pd, pb, bn[0], bn[1], bn[2], bn[3]);
                }
            } else {
                int ix = atomicAdd(&s_nnew, 1);
                newlist[ix] = ((int)p << 5) | t;
                v[p] = 0.f;
            }
        }
    }
    if (t < 64) {
#pragma unroll
        for (int d = 1; d < 64; d <<= 1) {
            d_ce += __shfl_xor(d_ce, d);
            d_loc += __shfl_xor(d_loc, d);
        }
        if (t == 0) {
            if (d_ce != 0.f)  atomicAdd(&sacc[0], d_ce);
            if (d_loc != 0.f) atomicAdd(&sacc[1], d_loc);
        }
    }
    if (t < MBLK * 3) atomicAdd(&sacc[t % 3], pacc[(size_t)n * MBLK * 3 + t]);
    __syncthreads();

    const int nn = s_nnew;
    {
        const int hl = lane & 31;
        float nce = 0.f, nloc = 0.f, nop = 0.f;
        for (int i = wave; i < nn; i += 8) {
            int e = newlist[i];
            int p = e >> 5, bm = e & 31;
            size_t idx = (size_t)n * PP + p;
            const float* row = pred_cls + idx * NCLS;
            bool al = lane < 32;
            float a = al ? row[hl] : -INFINITY;
            float b = al ? row[hl + 32] : -INFINITY;
            float c = (al && hl < NCLS - 64) ? row[hl + 64] : -INFINITY;
            float mx = fmaxf(fmaxf(a, b), c);
#pragma unroll
            for (int d = 1; d < 32; d <<= 1) mx = fmaxf(mx, __shfl_xor(mx, d));
            float se = al ? (expf(a - mx) + expf(b - mx)
                             + ((hl < NCLS - 64) ? expf(c - mx) : 0.f)) : 0.f;
#pragma unroll
            for (int d = 1; d < 32; d <<= 1) se += __shfl_xor(se, d);
            if (lane == 0) {
                nce += mx + logf(se) - row[labels[n * MM + bm]];
            } else if (lane == 1) {
                float4 pb = *(const float4*)(priors + (size_t)p * 4);
                float4 pd = *(const float4*)(pred_boxes + idx * 4);
                const float* bb = boxes + ((size_t)n * MM + bm) * 4;
                nloc += locv(pd, pb, bb[0], bb[1], bb[2], bb[3]);
            } else if (lane == 2) {
                float o = obj[idx];
                nop += (o - 1.0f) * (o - 1.0f);
            }
        }
        if (nce != 0.f)  atomicAdd(&sacc[0], nce);
        if (nloc != 0.f) atomicAdd(&sacc[1], nloc);
        if (nop != 0.f)  atomicAdd(&sacc[2], nop);
    }
    __syncthreads();
    if (t == 0) s_tot = s_nat + s_nnew;
    __syncthreads();
    const int s_tot_v = s_tot;
    int k = s_tot_v * 3; if (k > PP) k = PP;

    float result = 0.f;
    if (k >= PP) {
        float s = 0.f;
        for (int i = t; i < N4; i += 512) {
            float4 q = v4[i]; s += q.x + q.y + q.z + q.w;
        }
#pragma unroll
        for (int d = 32; d > 0; d >>= 1) s += __shfl_down(s, d);
        if ((t & 63) == 0) wred[wave] = s;
        __syncthreads();
        if (t == 0) { for (int i = 0; i < 8; i++) result += wred[i]; }
    } else if (k > 0) {
        __shared__ unsigned hist[HB];
        __shared__ unsigned ssc[512];
        __shared__ unsigned cand[CAPL];
        __shared__ int s_c, s_d, s_rem;
        __shared__ unsigned s_cur;
        __shared__ int s_rr;
        __shared__ unsigned rh[128];

        for (int i = t; i < HB; i += 512) hist[i] = 0;
        if (t == 0) s_c = 0;
        __syncthreads();

        for (int i = t; i < N4; i += 512) {
            float4 q = v4[i];
            atomicAdd(&hist[__float_as_uint(q.x) >> BSH], 1u);
            atomicAdd(&hist[__float_as_uint(q.y) >> BSH], 1u);
            atomicAdd(&hist[__float_as_uint(q.z) >> BSH], 1u);
            atomicAdd(&hist[__float_as_uint(q.w) >> BSH], 1u);
        }
        __syncthreads();

        unsigned csum = 0;
#pragma unroll
        for (int j = 0; j < 8; j++) csum += hist[4095 - 8 * t - j];
        ssc[t] = csum; __syncthreads();
        for (int off = 1; off < 512; off <<= 1) {
            unsigned x = (t >= off) ? ssc[t - off] : 0u;
            __syncthreads(); ssc[t] += x; __syncthreads();
        }
        unsigned incl = ssc[t], excl = incl - csum;
        if (excl < (unsigned)k && incl >= (unsigned)k) {
            unsigned cum = excl;
#pragma unroll
            for (int j = 0; j < 8; j++) {
                int b = 4095 - 8 * t - j; unsigned h = hist[b];
                if (cum + h >= (unsigned)k) { s_d = b; s_rem = (int)((unsigned)k - cum); break; }
                cum += h;
            }
        }
        __syncthreads();
        const int d = s_d; const int rem0 = s_rem;

        float ms = 0.f;
        for (int i = t; i < N4; i += 512) {
            float4 q = v4[i];
#define HND(C) { unsigned b = __float_as_uint(C); int bn = (int)(b >> BSH); \
            if (bn > d) ms += (C); \
            else if (bn == d) { int ix = atomicAdd(&s_c, 1); if (ix < CAPL) cand[ix] = b; } }
            HND(q.x) HND(q.y) HND(q.z) HND(q.w)
#undef HND
        }
        __syncthreads();
        const int C = s_c;
        const bool okl = (C <= CAPL);

        unsigned cur = (unsigned)d << BSH; int rem = rem0;
        const int shs[3] = {11, 4, 0};
        const int wbs[3] = {7, 7, 4};
        for (int ps = 0; ps < 3; ps++) {
            const int sh = shs[ps], wb = wbs[ps], W = 1 << wb;
            if (t < W) rh[t] = 0;
            __syncthreads();
            if (okl) {
                for (int i = t; i < C; i += 512) {
                    unsigned b = cand[i];
                    if ((b >> (sh + wb)) == (cur >> (sh + wb)))
                        atomicAdd(&rh[(b >> sh) & (W - 1)], 1u);
                }
            } else {
                for (int i = t; i < PP; i += 512) {
                    unsigned b = __float_as_uint(v[i]);
                    if ((b >> (sh + wb)) == (cur >> (sh + wb)))
                        atomicAdd(&rh[(b >> sh) & (W - 1)], 1u);
                }
            }
            __syncthreads();
            if (t == 0) {
                unsigned cum = 0; int dd;
                for (dd = W - 1; dd > 0; --dd) {
                    unsigned h = rh[dd];
                    if (cum + h >= (unsigned)rem) break;
                    cum += h;
                }
                s_cur = cur | ((unsigned)dd << sh);
                s_rr = rem - (int)cum;
            }
            __syncthreads();
            cur = s_cur; rem = s_rr;
            __syncthreads();
        }
        const unsigned thr = cur;
        const float thrv = __uint_as_float(thr);

        float sg = ms, cg = 0.f;
        if (okl) {
            for (int i = t; i < C; i += 512) {
                unsigned b = cand[i];
                if (b > thr) { sg += __uint_as_float(b); cg += 1.f; }
            }
        } else {
            for (int i = t; i < PP; i += 512) {
                unsigned b = __float_as_uint(v[i]);
                if ((int)(b >> BSH) == d && b > thr) { sg += __uint_as_float(b); cg += 1.f; }
            }
        }
#pragma unroll
        for (int dd = 32; dd > 0; dd >>= 1) {
            sg += __shfl_down(sg, dd);
            cg += __shfl_down(cg, dd);
        }
        if ((t & 63) == 0) { wred[wave] = sg; wred2[wave] = cg; }
        __syncthreads();
        if (t == 0) {
            float S = 0.f, Cc = 0.f;
            for (int i = 0; i < 8; i++) { S += wred[i]; Cc += wred2[i]; }
            result = S + ((float)rem0 - Cc) * thrv;
        }
    }

    if (t == 0) {
        pcnt[n] = s_tot_v;
        iacc[n] = make_float4(sacc[0], sacc[1], sacc[2], result);
        __threadfence();
        int old = atomicAdd(done, 1);
        if (old == NB - 1) {
            __threadfence();
            int np = 0, den = 0; float ce = 0.f, lc = 0.f, op = 0.f, hs = 0.f;
            for (int i = 0; i < NB; i++) {
                int c = pcnt[i];
                np += c;
                int kk = c * 3; if (kk > PP) kk = PP;
                den += kk;
                float4 a = iacc[i];
                ce += a.x; lc += a.y; op += a.z; hs += a.w;
            }
            float npf = (float)np;
            out[0] = ce / npf + op / npf
                   + hs / fmaxf((float)den, 1.0f)
                   + lc / (npf * 4.0f);
        }
    }
}

extern "C" void kernel_launch(void* const* d_in, const int* in_sizes, int n_in,
                              void* d_out, int out_size, void* d_ws, size_t ws_size,
                              hipStream_t stream) {
    const float* pred_boxes = (const float*)d_in[0];
    const float* pred_cls   = (const float*)d_in[1];
    const float* pred_obj   = (const float*)d_in[2];
    const float* priors     = (const float*)d_in[3];
    const float* boxes      = (const float*)d_in[4];
    const int*   labels     = (const int*)d_in[5];

    char* ws = (char*)d_ws;
    int* done  = (int*)(ws + WS_DONE);
    int* pcnt  = (int*)(ws + WS_PCNT);
    float4* iacc = (float4*)(ws + WS_IACC);
    float* pacc = (float*)(ws + WS_PACC);
    int* cpart = (int*)(ws + WS_CPART);
    unsigned long long* bkeyp = (unsigned long long*)(ws + WS_BKEYP);
    unsigned* posbit = (unsigned*)(ws + WS_POSBIT);
    unsigned char* m8 = (unsigned char*)(ws + WS_M8);
    float* val = (float*)(ws + WS_VAL);

    k_match<<<dim3(MBLK, NB), 256, 0, stream>>>(priors, boxes, pred_obj, pred_boxes,
                                                pred_cls, labels, bkeyp, posbit, m8,
                                                val, cpart, pacc, done);
    k_fin<<<NB, 512, 0, stream>>>(priors, boxes, pred_obj, pred_boxes, pred_cls,
                                  labels, bkeyp, posbit, m8, cpart, pacc, val,
                                  pcnt, iacc, done, (float*)d_out);
}